// Round 15
// baseline (427.415 us; speedup 1.0000x reference)
//
#include <hip/hip_runtime.h>
#include <stdint.h>

#define BDIM 32
#define CDIM 32
#define LDIM 1024
#define VDIM 4096
#define BCL (BDIM*CDIM*LDIM)

// zero-cost pin: forces the SCALAR value to live in an arch VGPR at this point
// (defeats AGPR-parking; emits no instructions). NOTE: scalar floats only --
// "+v" on float4 fails to compile ("tied indirect register inputs", round 13).
#define PIN_V(x) asm volatile("" : "+v"(x))

// ---------------------------------------------------------------- init
__global__ void init_kernel(const float* __restrict__ f, const float* __restrict__ emb,
                            float* __restrict__ f_rest, float* __restrict__ f_hat,
                            float* __restrict__ e_sq, float* __restrict__ loss_acc,
                            unsigned* __restrict__ done_ctr,
                            unsigned long long* __restrict__ keys, int nkeys) {
    int i = blockIdx.x * blockDim.x + threadIdx.x;
    if (i < BCL) { f_rest[i] = f[i]; f_hat[i] = 0.0f; }
    if (i < VDIM) {
        const float4* e4 = (const float4*)(emb + (size_t)i * CDIM);
        float s = 0.f;
#pragma unroll
        for (int k = 0; k < 8; ++k) {
            float4 v = e4[k];
            s += v.x*v.x; s += v.y*v.y; s += v.z*v.z; s += v.w*v.w;
        }
        e_sq[i] = s;
    }
    if (i < nkeys) keys[i] = ~0ull;
    if (i == 0) { *loss_acc = 0.f; *done_ctr = 0u; }
}

// ---------------------------------------------------------------- VQ argmin: lane-per-query scan
// ROUND-15 == ROUND-14 resubmit (r14 was an infra failure; r13 a compile failure).
// 2 queries x 2 codes per iteration. r12 diagnosis: LDS-PIPE-THROUGHPUT bound (~5.8 cy
// per broadcast ds_read_b128; 16 reads per 64 FMA = 2.7x oversubscribed vs VALU;
// occupancy already fine at 58%). Fix: amortize each e-read over 2 queries -> 16 reads
// per 128 FMA (LDS ~85us, VALU ~62us at pl=1024). r8's 2q attempt was AGPR-parked at a
// 64-reg target; scalar PIN_V inside the loop makes parking cost 2 moves/value/iter ->
// allocator keeps z in arch VGPRs. Chains c=0..31 sequential per query, codes ascending,
// strict < (bit-identical results + first-index tie-break).
__global__ __launch_bounds__(256) void vq_scan(
    const float* __restrict__ f_rest, const float* __restrict__ z_buf,
    const float* __restrict__ emb, const float* __restrict__ e_sq,
    unsigned long long* __restrict__ keys,
    int lpl, int s, int NQ, int VC, int vchunks)
{
    const int pl = 1 << lpl;
    const int t  = threadIdx.x;
    const int qg = blockIdx.x / vchunks;    // 512-query group
    const int vc = blockIdx.x % vchunks;
    const int vb = vc * VC;

    __shared__ __align__(16) float e_ls[128 * 32];   // up to 128 codes x 32 ch (16 KB)
    __shared__ float esq_ls[128];

    // ---- stage code chunk (linear, coalesced; VC*8 float4s over 256 threads)
    {
        const float4* src = (const float4*)emb + (size_t)vb * 8;
        float4* dst = (float4*)e_ls;
        for (int x = t; x < VC * 8; x += 256) dst[x] = src[x];
        if (t < VC) esq_ls[t] = e_sq[vb + t];
    }

    // ---- load this lane's two query vectors into registers (scalars)
    const int q0 = qg * 512 + t;
    const int q1 = q0 + 256;
    const int qc0 = (q0 < NQ) ? q0 : NQ - 1;
    const int qc1 = (q1 < NQ) ? q1 : NQ - 1;

    float z0[32], z1[32];
    if (z_buf) {
        const float4* p0 = (const float4*)(z_buf + (size_t)qc0 * 32);
        const float4* p1 = (const float4*)(z_buf + (size_t)qc1 * 32);
#pragma unroll
        for (int c4 = 0; c4 < 8; ++c4) {
            float4 a = p0[c4], b = p1[c4];
            z0[c4*4+0] = a.x; z0[c4*4+1] = a.y; z0[c4*4+2] = a.z; z0[c4*4+3] = a.w;
            z1[c4*4+0] = b.x; z1[c4*4+1] = b.y; z1[c4*4+2] = b.z; z1[c4*4+3] = b.w;
        }
    } else {
        int b0 = qc0 >> lpl, j0 = qc0 & (pl - 1);
        int b1 = qc1 >> lpl, j1 = qc1 & (pl - 1);
        if (pl == LDIM) {
            const float* p0 = f_rest + b0 * (CDIM * LDIM) + j0;
            const float* p1 = f_rest + b1 * (CDIM * LDIM) + j1;
#pragma unroll
            for (int c = 0; c < 32; ++c) { z0[c] = p0[c * LDIM]; z1[c] = p1[c * LDIM]; }
        } else {
            int col0 = j0 * s + (s >> 1) - 1;
            int col1 = j1 * s + (s >> 1) - 1;
            const float* p0 = f_rest + b0 * (CDIM * LDIM) + col0;
            const float* p1 = f_rest + b1 * (CDIM * LDIM) + col1;
#pragma unroll
            for (int c = 0; c < 32; ++c) {
                z0[c] = 0.5f * (p0[c * LDIM] + p0[c * LDIM + 1]);
                z1[c] = 0.5f * (p1[c * LDIM] + p1[c * LDIM + 1]);
            }
        }
    }

    __syncthreads();

    // ---- scan: biased distance d' = e_sq - 2*dot (zz const per query)
    float bd0 = 3.4e38f, bd1 = 3.4e38f;
    int bv0 = 0, bv1 = 0;

#pragma unroll 1
    for (int v = 0; v < VC; v += 2) {
        // pin z in arch VGPRs every iteration (free; scalar tied operands compile)
#pragma unroll
        for (int c = 0; c < 32; ++c) { PIN_V(z0[c]); PIN_V(z1[c]); }

        const float4* er0 = (const float4*)&e_ls[(size_t)v * 32];
        const float4* er1 = er0 + 8;
        float es0 = esq_ls[v];
        float es1 = esq_ls[v + 1];

        float4 e0 = er0[0], e1 = er1[0];
        float a00 = z0[0] * e0.x,        a01 = z0[0] * e1.x;
        float a10 = z1[0] * e0.x,        a11 = z1[0] * e1.x;
        a00 = fmaf(z0[1], e0.y, a00);    a01 = fmaf(z0[1], e1.y, a01);
        a10 = fmaf(z1[1], e0.y, a10);    a11 = fmaf(z1[1], e1.y, a11);
        a00 = fmaf(z0[2], e0.z, a00);    a01 = fmaf(z0[2], e1.z, a01);
        a10 = fmaf(z1[2], e0.z, a10);    a11 = fmaf(z1[2], e1.z, a11);
        a00 = fmaf(z0[3], e0.w, a00);    a01 = fmaf(z0[3], e1.w, a01);
        a10 = fmaf(z1[3], e0.w, a10);    a11 = fmaf(z1[3], e1.w, a11);
#pragma unroll
        for (int c4 = 1; c4 < 8; ++c4) {
            e0 = er0[c4]; e1 = er1[c4];
            a00 = fmaf(z0[c4*4+0], e0.x, a00);  a01 = fmaf(z0[c4*4+0], e1.x, a01);
            a10 = fmaf(z1[c4*4+0], e0.x, a10);  a11 = fmaf(z1[c4*4+0], e1.x, a11);
            a00 = fmaf(z0[c4*4+1], e0.y, a00);  a01 = fmaf(z0[c4*4+1], e1.y, a01);
            a10 = fmaf(z1[c4*4+1], e0.y, a10);  a11 = fmaf(z1[c4*4+1], e1.y, a11);
            a00 = fmaf(z0[c4*4+2], e0.z, a00);  a01 = fmaf(z0[c4*4+2], e1.z, a01);
            a10 = fmaf(z1[c4*4+2], e0.z, a10);  a11 = fmaf(z1[c4*4+2], e1.z, a11);
            a00 = fmaf(z0[c4*4+3], e0.w, a00);  a01 = fmaf(z0[c4*4+3], e1.w, a01);
            a10 = fmaf(z1[c4*4+3], e0.w, a10);  a11 = fmaf(z1[c4*4+3], e1.w, a11);
        }
        float d00 = fmaf(a00, -2.0f, es0);
        float d01 = fmaf(a01, -2.0f, es1);
        float d10 = fmaf(a10, -2.0f, es0);
        float d11 = fmaf(a11, -2.0f, es1);
        if (d00 < bd0) { bd0 = d00; bv0 = vb + v; }
        if (d01 < bd0) { bd0 = d01; bv0 = vb + v + 1; }
        if (d10 < bd1) { bd1 = d10; bv1 = vb + v; }
        if (d11 < bd1) { bd1 = d11; bv1 = vb + v + 1; }
    }

    if (q0 < NQ) {
        unsigned ud = __float_as_uint(bd0);
        ud = (ud & 0x80000000u) ? ~ud : (ud | 0x80000000u);
        atomicMin(&keys[q0], ((unsigned long long)ud << 32) | (unsigned)bv0);
    }
    if (q1 < NQ) {
        unsigned ud = __float_as_uint(bd1);
        ud = (ud & 0x80000000u) ? ~ud : (ud | 0x80000000u);
        atomicMin(&keys[q1], ((unsigned long long)ud << 32) | (unsigned)bv1);
    }
}

// ---------------------------------------------------------------- fused gather+upsample+phi+update+loss
// 64-element L-chunks (grid 16 x 32). Extras: resets next scale's key buffer (ping-pong);
// writes next scale's downsampled queries into z_buf (bit-identical 0.5*(fr[col]+fr[col+1]),
// via LDS since col+1 may belong to a neighboring thread); last scale finalizes the loss.
__global__ __launch_bounds__(256) void fuse_kernel(
    const float* __restrict__ f, const float* __restrict__ emb,
    const unsigned long long* __restrict__ keys,
    unsigned long long* __restrict__ keys_next, int nq_next,
    float* __restrict__ z_next, int s_next,
    const float* __restrict__ w, const float* __restrict__ bias,
    float* __restrict__ f_rest, float* __restrict__ f_hat,
    float* __restrict__ loss_acc, unsigned* __restrict__ done_ctr,
    float* __restrict__ out_loss, int pl)
{
    const int t  = threadIdx.x;
    const int b  = blockIdx.y;
    const int l0 = blockIdx.x * 64;

    // reset next scale's keys (different buffer than 'keys'; safe to do immediately)
    if (keys_next) {
        int x = (b * gridDim.x + blockIdx.x) * 256 + t;   // 512*256 = 131072 >= nq_next
        if (x < nq_next) keys_next[x] = ~0ull;
    }

    __shared__ float w_s[3072];      // [o][i][k]
    __shared__ float b_s[32];
    __shared__ float hs[32 * 68];    // [i][66 (+pad)] : col x -> l = l0 - 1 + x
    __shared__ float red[4];

    for (int x = t; x < 3072; x += 256) w_s[x] = w[x];
    if (t < 32) b_s[t] = bias[t];

    if (t < 66) {
        int l = l0 - 1 + t;
        if (l < 0 || l >= LDIM) {
#pragma unroll
            for (int i = 0; i < 32; ++i) hs[i * 68 + t] = 0.f;
        } else {
            int lo, hi; float wg;
            if (pl == LDIM) { lo = l; hi = l; wg = 0.f; }
            else {
                float pos = (l + 0.5f) * ((float)pl / 1024.0f) - 0.5f;
                pos = fminf(fmaxf(pos, 0.f), (float)(pl - 1));
                lo = (int)floorf(pos);
                hi = min(lo + 1, pl - 1);
                wg = pos - (float)lo;
            }
            int v0 = (int)(keys[b * pl + lo] & 0xFFFFFFFFull);
            int v1 = (int)(keys[b * pl + hi] & 0xFFFFFFFFull);
            const float4* e0 = (const float4*)(emb + (size_t)v0 * 32);
            const float4* e1 = (const float4*)(emb + (size_t)v1 * 32);
            float om = 1.0f - wg;
#pragma unroll
            for (int i4 = 0; i4 < 8; ++i4) {
                float4 a = e0[i4]; float4 c = e1[i4];
                hs[(i4*4+0) * 68 + t] = a.x * om + c.x * wg;
                hs[(i4*4+1) * 68 + t] = a.y * om + c.y * wg;
                hs[(i4*4+2) * 68 + t] = a.z * om + c.z * wg;
                hs[(i4*4+3) * 68 + t] = a.w * om + c.w * wg;
            }
        }
    }
    __syncthreads();

    const int o  = t >> 3;        // output channel, fixed per thread (w reuse x8)
    const int lg = t & 7;         // 8 consecutive l's per thread
    const float* wrow = &w_s[o * 96];
    float acc[8];
#pragma unroll
    for (int u = 0; u < 8; ++u) acc[u] = 0.f;
    const int hbase = lg * 8;     // hs col for l = l0 + lg*8 - 1

    for (int i = 0; i < 32; ++i) {
        float w0 = wrow[i * 3 + 0], w1 = wrow[i * 3 + 1], w2 = wrow[i * 3 + 2];
        const float* hrow = &hs[i * 68 + hbase];
        float hw[10];
#pragma unroll
        for (int x = 0; x < 10; ++x) hw[x] = hrow[x];
#pragma unroll
        for (int u = 0; u < 8; ++u) {
            acc[u] = fmaf(w0, hw[u], acc[u]);
            acc[u] = fmaf(w1, hw[u + 1], acc[u]);
            acc[u] = fmaf(w2, hw[u + 2], acc[u]);
        }
    }

    float lsum = 0.f;
    float frv[8];
    const int gbase = (b * 32 + o) * LDIM + l0 + lg * 8;
#pragma unroll
    for (int u = 0; u < 8; ++u) {
        float hval = hs[o * 68 + lg * 8 + 1 + u];
        float y = acc[u] + b_s[o];
        float ph = 0.5f * hval + 0.5f * y;    // h*(1-RESI) + (conv+b)*RESI, RESI=0.5
        int gi = gbase + u;
        float fh = f_hat[gi] + ph;
        f_hat[gi] = fh;
        float fr = f_rest[gi] - ph;
        f_rest[gi] = fr;
        frv[u] = fr;
        float df = fh - f[gi];
        lsum = fmaf(df, df, lsum);
    }

    // ---- write next scale's downsampled queries (z) from the fresh f_rest values.
    // s_next in {1,4,16,64}; col = j*s + s/2 - 1 stays inside [l0, l0+62] for s<=64.
    if (z_next) {
        __syncthreads();              // all hval reads done
#pragma unroll
        for (int u = 0; u < 8; ++u) hs[o * 68 + lg * 8 + u] = frv[u];   // [c][l-l0]
        __syncthreads();
        int npos = 64 / s_next;
        int qn_base = b * (LDIM / s_next) + l0 / s_next;
        for (int v = t; v < npos * 32; v += 256) {
            int jl = v >> 5, c = v & 31;
            float zv;
            if (s_next == 1) zv = hs[c * 68 + jl];
            else {
                int cl = jl * s_next + (s_next >> 1) - 1;
                zv = 0.5f * (hs[c * 68 + cl] + hs[c * 68 + cl + 1]);
            }
            z_next[(size_t)(qn_base + jl) * 32 + c] = zv;
        }
    }

#pragma unroll
    for (int off = 32; off > 0; off >>= 1) lsum += __shfl_down(lsum, off, 64);
    if ((t & 63) == 0) red[t >> 6] = lsum;
    __syncthreads();
    if (t == 0) {
        atomicAdd(loss_acc, red[0] + red[1] + red[2] + red[3]);
        if (out_loss) {
            __threadfence();
            unsigned old = atomicAdd(done_ctr, 1u);
            if (old == (unsigned)(gridDim.x * gridDim.y - 1)) {
                float lv = atomicAdd(loss_acc, 0.0f);   // coherent read after all adds
                *out_loss = lv * (1.25f / (6.0f * (float)BCL));
            }
        }
    }
}

// ---------------------------------------------------------------- launch
extern "C" void kernel_launch(void* const* d_in, const int* in_sizes, int n_in,
                              void* d_out, int out_size, void* d_ws, size_t ws_size,
                              hipStream_t stream)
{
    const float* f    = (const float*)d_in[0];
    const float* emb  = (const float*)d_in[1];
    const float* phiw = (const float*)d_in[2];
    const float* phib = (const float*)d_in[3];

    float* f_hat    = (float*)d_out;        // BCL floats
    float* out_loss = f_hat + BCL;          // +1 float

    const int pls[6]   = {1, 4, 16, 64, 256, 1024};
    const int lpls[6]  = {0, 2, 4, 6, 8, 10};
    // 512 queries/block (2 per lane). VC = VDIM/vch <= 128 (16KB e-tile).
    // pl=1024: 64 qgroups x 32 = 2048 blocks, VC=128. pl=256: 16 x 32 = 512.
    const int vch[6]   = {64, 64, 64, 64, 32, 32};
    const int pidx[6]  = {0, 0, 1, 2, 3, 3};     // PhiPartiallyShared static tick lookup
    const int snx[6]   = {256, 64, 16, 4, 1, 0}; // s of scale si+1 (0 = none)

    char* ws = (char*)d_ws;
    float* f_rest             = (float*)ws;                            // 4 MB
    unsigned long long* keysA = (unsigned long long*)(ws + (size_t)BCL * 4);   // 256 KB

    // Layout: f_rest | keysA | (keysB) | (z_buf 4MB) | e_sq | loss | ctr
    size_t base = (size_t)BCL * 4;
    size_t need_pp   = base + (size_t)65536 * 8 + (size_t)VDIM * 4 + 64;
    size_t need_full = need_pp + (size_t)32768 * 32 * 4;
    bool pp   = ws_size >= need_pp;
    bool zb   = ws_size >= need_full;
    unsigned long long* keysB = pp ? keysA + 32768 : keysA;
    size_t keys_bytes = pp ? (size_t)65536 * 8 : (size_t)32768 * 8;
    float* z_buf = zb ? (float*)(ws + base + keys_bytes) : nullptr;
    size_t zoff  = zb ? (size_t)32768 * 32 * 4 : 0;
    float* e_sq        = (float*)(ws + base + keys_bytes + zoff);
    float* loss_acc    = e_sq + VDIM;
    unsigned* done_ctr = (unsigned*)(loss_acc + 1);

    init_kernel<<<dim3((BCL + 255) / 256), 256, 0, stream>>>(
        f, emb, f_rest, f_hat, e_sq, loss_acc, done_ctr, keysA, 32768);

    for (int si = 0; si < 6; ++si) {
        int pl = pls[si];
        int s  = LDIM / pl;
        int NQ = BDIM * pl;
        int qgroups = (NQ + 511) >> 9;
        int VC = VDIM / vch[si];
        unsigned long long* k  = (si & 1) ? keysB : keysA;
        unsigned long long* kn = (si < 5 && pp) ? ((si & 1) ? keysA : keysB) : nullptr;
        int nq_next = (si < 5) ? BDIM * pls[si + 1] : 0;
        if (!pp && si > 0) hipMemsetAsync(k, 0xFF, (size_t)NQ * 8, stream);
        const float* zread = (zb && si >= 2) ? z_buf : nullptr;
        float* zwrite      = (zb && si >= 1 && si <= 4) ? z_buf : nullptr;
        vq_scan<<<dim3(qgroups * vch[si]), 256, 0, stream>>>(
            f_rest, zread, emb, e_sq, k, lpls[si], s, NQ, VC, vch[si]);
        fuse_kernel<<<dim3(16, 32), 256, 0, stream>>>(
            f, emb, k, kn, nq_next, zwrite, snx[si],
            phiw + (size_t)pidx[si] * 3072, phib + (size_t)pidx[si] * 32,
            f_rest, f_hat, loss_acc, done_ctr,
            (si == 5) ? out_loss : nullptr, pl);
    }
}

// Round 16
// 318.667 us; speedup vs baseline: 1.3413x; 1.3413x over previous
//
#include <hip/hip_runtime.h>
#include <stdint.h>

#define BDIM 32
#define CDIM 32
#define LDIM 1024
#define VDIM 4096
#define BCL (BDIM*CDIM*LDIM)

typedef _Float16 f16x8 __attribute__((ext_vector_type(8)));
typedef float f32x4 __attribute__((ext_vector_type(4)));

// zero-cost pin (scalar floats only; float4 "+v" doesn't compile - r13)
#define PIN_V(x) asm volatile("" : "+v"(x))

// ---------------------------------------------------------------- init
__global__ void init_kernel(const float* __restrict__ f, const float* __restrict__ emb,
                            float* __restrict__ f_rest, float* __restrict__ f_hat,
                            float* __restrict__ e_sq,
                            _Float16* __restrict__ eh, _Float16* __restrict__ el,
                            float* __restrict__ loss_acc, unsigned* __restrict__ done_ctr,
                            unsigned long long* __restrict__ keys, int nkeys) {
    int i = blockIdx.x * blockDim.x + threadIdx.x;
    if (i < BCL) { f_rest[i] = f[i]; f_hat[i] = 0.0f; }
    if (i < VDIM) {
        const float* e = emb + (size_t)i * CDIM;
        float s = 0.f;
#pragma unroll
        for (int k = 0; k < 32; ++k) {
            float v = e[k];
            s = fmaf(v, v, s);
            if (eh) {
                _Float16 h = (_Float16)v;
                float r = v - (float)h;
                eh[(size_t)i*32 + k] = h;
                el[(size_t)i*32 + k] = (_Float16)r;
            }
        }
        e_sq[i] = s;
    }
    if (i < nkeys) keys[i] = ~0ull;
    if (i == 0) { *loss_acc = 0.f; *done_ctr = 0u; }
}

// ---------------------------------------------------------------- VQ argmin via MFMA (si>=2)
// Distance GEMM D[q][v] = sum_c z[q][c]*e[v][c], K=32 = one mfma_f32_16x16x32_f16 tile.
// FP32 accuracy via 2-way fp16 split: z=zh+zl, e=eh+el -> 4 chained MFMAs; residual
// capture to 2^-23 rel (tighter than the fp32-chain reorder error already tolerated).
// Rationale: 10 rounds of fp32-VALU scans were allocator-bound (AGPR parking) at ~2.4x
// their floor; MFMA makes AGPR-affinity an asset. Layouts: A row=l&15,k=(l>>4)*8+j;
// B col=l&15, same k; C/D col=l&15,row=(l>>4)*4+i (m89-verified, dtype-independent).
// Block: 4 waves x 2 q-tiles = 128 queries, one VC-code chunk staged in LDS.
// Argmin: per-lane (bd,bv)[4] per tile; 4x shfl_xor 16-lane min; 1 atomicMin/q/chunk.
__global__ __launch_bounds__(256) void vq_mfma(
    const _Float16* __restrict__ z_hi, const _Float16* __restrict__ z_lo,
    const _Float16* __restrict__ e_hi, const _Float16* __restrict__ e_lo,
    const float* __restrict__ e_sq, unsigned long long* __restrict__ keys,
    int NQ, int VC, int vchunks)
{
    const int t = threadIdx.x;
    const int lane = t & 63;
    const int w = t >> 6;
    const int qg = blockIdx.x / vchunks;
    const int vc = blockIdx.x % vchunks;
    const int vb = vc * VC;

    __shared__ __align__(16) _Float16 eh_ls[256*32];   // 16 KB
    __shared__ __align__(16) _Float16 el_ls[256*32];   // 16 KB
    __shared__ float esq_ls[256];

    {
        const float4* sH = (const float4*)(e_hi + (size_t)vb*32);
        const float4* sL = (const float4*)(e_lo + (size_t)vb*32);
        float4* dH = (float4*)eh_ls; float4* dL = (float4*)el_ls;
        int n4 = VC * 4;                 // VC*32 halves / 8 per float4
        for (int x = t; x < n4; x += 256) { dH[x] = sH[x]; dL[x] = sL[x]; }
        for (int v = t; v < VC; v += 256) esq_ls[v] = e_sq[vb + v];
    }

    const int fr = lane & 15;            // fragment row/col
    const int kq = lane >> 4;            // k-block (8 channels)
    const int qbase = qg*128 + w*32;     // NQ multiple of 128 for si>=2: no tail
    const int q0 = qbase + fr;
    f16x8 a0h = *(const f16x8*)(z_hi + (size_t)q0*32 + kq*8);
    f16x8 a0l = *(const f16x8*)(z_lo + (size_t)q0*32 + kq*8);
    f16x8 a1h = *(const f16x8*)(z_hi + (size_t)(q0+16)*32 + kq*8);
    f16x8 a1l = *(const f16x8*)(z_lo + (size_t)(q0+16)*32 + kq*8);

    __syncthreads();

    float bd0[4], bd1[4]; int bv0[4], bv1[4];
#pragma unroll
    for (int i = 0; i < 4; ++i) { bd0[i]=3.4e38f; bd1[i]=3.4e38f; bv0[i]=0; bv1[i]=0; }

    for (int vt = 0; vt < VC; vt += 16) {
        const f16x8 bh = *(const f16x8*)(eh_ls + (size_t)(vt+fr)*32 + kq*8);
        const f16x8 bl = *(const f16x8*)(el_ls + (size_t)(vt+fr)*32 + kq*8);
        f32x4 acc0 = {0.f,0.f,0.f,0.f};
        f32x4 acc1 = {0.f,0.f,0.f,0.f};
        acc0 = __builtin_amdgcn_mfma_f32_16x16x32_f16(a0h, bh, acc0, 0,0,0);
        acc0 = __builtin_amdgcn_mfma_f32_16x16x32_f16(a0h, bl, acc0, 0,0,0);
        acc0 = __builtin_amdgcn_mfma_f32_16x16x32_f16(a0l, bh, acc0, 0,0,0);
        acc0 = __builtin_amdgcn_mfma_f32_16x16x32_f16(a0l, bl, acc0, 0,0,0);
        acc1 = __builtin_amdgcn_mfma_f32_16x16x32_f16(a1h, bh, acc1, 0,0,0);
        acc1 = __builtin_amdgcn_mfma_f32_16x16x32_f16(a1h, bl, acc1, 0,0,0);
        acc1 = __builtin_amdgcn_mfma_f32_16x16x32_f16(a1l, bh, acc1, 0,0,0);
        acc1 = __builtin_amdgcn_mfma_f32_16x16x32_f16(a1l, bl, acc1, 0,0,0);

        float es = esq_ls[vt + fr];
        int vg = vb + vt + fr;
#pragma unroll
        for (int i = 0; i < 4; ++i) {
            float d0 = fmaf(acc0[i], -2.0f, es);
            if (d0 < bd0[i]) { bd0[i] = d0; bv0[i] = vg; }
            float d1 = fmaf(acc1[i], -2.0f, es);
            if (d1 < bd1[i]) { bd1[i] = d1; bv1[i] = vg; }
        }
    }

    // cross-lane argmin: group g=lanes 16g..16g+15 holds rows 4g..4g+3, cols 0..15
#pragma unroll
    for (int i = 0; i < 4; ++i) {
        unsigned u0 = __float_as_uint(bd0[i]);
        u0 = (u0 & 0x80000000u) ? ~u0 : (u0 | 0x80000000u);
        unsigned long long k0 = ((unsigned long long)u0 << 32) | (unsigned)bv0[i];
        unsigned u1 = __float_as_uint(bd1[i]);
        u1 = (u1 & 0x80000000u) ? ~u1 : (u1 | 0x80000000u);
        unsigned long long k1 = ((unsigned long long)u1 << 32) | (unsigned)bv1[i];
#pragma unroll
        for (int m = 1; m < 16; m <<= 1) {
            unsigned long long o0 = __shfl_xor(k0, m, 64); if (o0 < k0) k0 = o0;
            unsigned long long o1 = __shfl_xor(k1, m, 64); if (o1 < k1) k1 = o1;
        }
        if (fr == 0) {
            int q = qbase + kq*4 + i;
            atomicMin(&keys[q], k0);
            atomicMin(&keys[q + 16], k1);
        }
    }
}

// ---------------------------------------------------------------- VQ argmin: lane-per-query scan
// (r15 kernel, kept for si 0,1 -- NQ=32/128, reads f_rest directly -- and as fallback.)
__global__ __launch_bounds__(256) void vq_scan(
    const float* __restrict__ f_rest, const float* __restrict__ z_buf,
    const float* __restrict__ emb, const float* __restrict__ e_sq,
    unsigned long long* __restrict__ keys,
    int lpl, int s, int NQ, int VC, int vchunks)
{
    const int pl = 1 << lpl;
    const int t  = threadIdx.x;
    const int qg = blockIdx.x / vchunks;
    const int vc = blockIdx.x % vchunks;
    const int vb = vc * VC;

    __shared__ __align__(16) float e_ls[128 * 32];
    __shared__ float esq_ls[128];

    {
        const float4* src = (const float4*)emb + (size_t)vb * 8;
        float4* dst = (float4*)e_ls;
        for (int x = t; x < VC * 8; x += 256) dst[x] = src[x];
        if (t < VC) esq_ls[t] = e_sq[vb + t];
    }

    const int q0 = qg * 512 + t;
    const int q1 = q0 + 256;
    const int qc0 = (q0 < NQ) ? q0 : NQ - 1;
    const int qc1 = (q1 < NQ) ? q1 : NQ - 1;

    float z0[32], z1[32];
    if (z_buf) {
        const float4* p0 = (const float4*)(z_buf + (size_t)qc0 * 32);
        const float4* p1 = (const float4*)(z_buf + (size_t)qc1 * 32);
#pragma unroll
        for (int c4 = 0; c4 < 8; ++c4) {
            float4 a = p0[c4], b = p1[c4];
            z0[c4*4+0] = a.x; z0[c4*4+1] = a.y; z0[c4*4+2] = a.z; z0[c4*4+3] = a.w;
            z1[c4*4+0] = b.x; z1[c4*4+1] = b.y; z1[c4*4+2] = b.z; z1[c4*4+3] = b.w;
        }
    } else {
        int b0 = qc0 >> lpl, j0 = qc0 & (pl - 1);
        int b1 = qc1 >> lpl, j1 = qc1 & (pl - 1);
        if (pl == LDIM) {
            const float* p0 = f_rest + b0 * (CDIM * LDIM) + j0;
            const float* p1 = f_rest + b1 * (CDIM * LDIM) + j1;
#pragma unroll
            for (int c = 0; c < 32; ++c) { z0[c] = p0[c * LDIM]; z1[c] = p1[c * LDIM]; }
        } else {
            int col0 = j0 * s + (s >> 1) - 1;
            int col1 = j1 * s + (s >> 1) - 1;
            const float* p0 = f_rest + b0 * (CDIM * LDIM) + col0;
            const float* p1 = f_rest + b1 * (CDIM * LDIM) + col1;
#pragma unroll
            for (int c = 0; c < 32; ++c) {
                z0[c] = 0.5f * (p0[c * LDIM] + p0[c * LDIM + 1]);
                z1[c] = 0.5f * (p1[c * LDIM] + p1[c * LDIM + 1]);
            }
        }
    }

    __syncthreads();

    float bd0 = 3.4e38f, bd1 = 3.4e38f;
    int bv0 = 0, bv1 = 0;

#pragma unroll 1
    for (int v = 0; v < VC; v += 2) {
#pragma unroll
        for (int c = 0; c < 32; ++c) { PIN_V(z0[c]); PIN_V(z1[c]); }

        const float4* er0 = (const float4*)&e_ls[(size_t)v * 32];
        const float4* er1 = er0 + 8;
        float es0 = esq_ls[v];
        float es1 = esq_ls[v + 1];

        float4 e0 = er0[0], e1 = er1[0];
        float a00 = z0[0] * e0.x,        a01 = z0[0] * e1.x;
        float a10 = z1[0] * e0.x,        a11 = z1[0] * e1.x;
        a00 = fmaf(z0[1], e0.y, a00);    a01 = fmaf(z0[1], e1.y, a01);
        a10 = fmaf(z1[1], e0.y, a10);    a11 = fmaf(z1[1], e1.y, a11);
        a00 = fmaf(z0[2], e0.z, a00);    a01 = fmaf(z0[2], e1.z, a01);
        a10 = fmaf(z1[2], e0.z, a10);    a11 = fmaf(z1[2], e1.z, a11);
        a00 = fmaf(z0[3], e0.w, a00);    a01 = fmaf(z0[3], e1.w, a01);
        a10 = fmaf(z1[3], e0.w, a10);    a11 = fmaf(z1[3], e1.w, a11);
#pragma unroll
        for (int c4 = 1; c4 < 8; ++c4) {
            e0 = er0[c4]; e1 = er1[c4];
            a00 = fmaf(z0[c4*4+0], e0.x, a00);  a01 = fmaf(z0[c4*4+0], e1.x, a01);
            a10 = fmaf(z1[c4*4+0], e0.x, a10);  a11 = fmaf(z1[c4*4+0], e1.x, a11);
            a00 = fmaf(z0[c4*4+1], e0.y, a00);  a01 = fmaf(z0[c4*4+1], e1.y, a01);
            a10 = fmaf(z1[c4*4+1], e0.y, a10);  a11 = fmaf(z1[c4*4+1], e1.y, a11);
            a00 = fmaf(z0[c4*4+2], e0.z, a00);  a01 = fmaf(z0[c4*4+2], e1.z, a01);
            a10 = fmaf(z1[c4*4+2], e0.z, a10);  a11 = fmaf(z1[c4*4+2], e1.z, a11);
            a00 = fmaf(z0[c4*4+3], e0.w, a00);  a01 = fmaf(z0[c4*4+3], e1.w, a01);
            a10 = fmaf(z1[c4*4+3], e0.w, a10);  a11 = fmaf(z1[c4*4+3], e1.w, a11);
        }
        float d00 = fmaf(a00, -2.0f, es0);
        float d01 = fmaf(a01, -2.0f, es1);
        float d10 = fmaf(a10, -2.0f, es0);
        float d11 = fmaf(a11, -2.0f, es1);
        if (d00 < bd0) { bd0 = d00; bv0 = vb + v; }
        if (d01 < bd0) { bd0 = d01; bv0 = vb + v + 1; }
        if (d10 < bd1) { bd1 = d10; bv1 = vb + v; }
        if (d11 < bd1) { bd1 = d11; bv1 = vb + v + 1; }
    }

    if (q0 < NQ) {
        unsigned ud = __float_as_uint(bd0);
        ud = (ud & 0x80000000u) ? ~ud : (ud | 0x80000000u);
        atomicMin(&keys[q0], ((unsigned long long)ud << 32) | (unsigned)bv0);
    }
    if (q1 < NQ) {
        unsigned ud = __float_as_uint(bd1);
        ud = (ud & 0x80000000u) ? ~ud : (ud | 0x80000000u);
        atomicMin(&keys[q1], ((unsigned long long)ud << 32) | (unsigned)bv1);
    }
}

// ---------------------------------------------------------------- fused gather+upsample+phi+update+loss
// 64-element L-chunks (grid 16 x 32). Resets next scale's key buffer (ping-pong);
// writes next scale's downsampled queries as fp16 hi/lo split (exact 2-way split:
// h=fp16(zv), l=fp16(zv-(float)h)); last scale finalizes the loss via done-counter.
__global__ __launch_bounds__(256) void fuse_kernel(
    const float* __restrict__ f, const float* __restrict__ emb,
    const unsigned long long* __restrict__ keys,
    unsigned long long* __restrict__ keys_next, int nq_next,
    _Float16* __restrict__ zh_next, _Float16* __restrict__ zl_next, int s_next,
    const float* __restrict__ w, const float* __restrict__ bias,
    float* __restrict__ f_rest, float* __restrict__ f_hat,
    float* __restrict__ loss_acc, unsigned* __restrict__ done_ctr,
    float* __restrict__ out_loss, int pl)
{
    const int t  = threadIdx.x;
    const int b  = blockIdx.y;
    const int l0 = blockIdx.x * 64;

    if (keys_next) {
        int x = (b * gridDim.x + blockIdx.x) * 256 + t;
        if (x < nq_next) keys_next[x] = ~0ull;
    }

    __shared__ float w_s[3072];
    __shared__ float b_s[32];
    __shared__ float hs[32 * 68];
    __shared__ float red[4];

    for (int x = t; x < 3072; x += 256) w_s[x] = w[x];
    if (t < 32) b_s[t] = bias[t];

    if (t < 66) {
        int l = l0 - 1 + t;
        if (l < 0 || l >= LDIM) {
#pragma unroll
            for (int i = 0; i < 32; ++i) hs[i * 68 + t] = 0.f;
        } else {
            int lo, hi; float wg;
            if (pl == LDIM) { lo = l; hi = l; wg = 0.f; }
            else {
                float pos = (l + 0.5f) * ((float)pl / 1024.0f) - 0.5f;
                pos = fminf(fmaxf(pos, 0.f), (float)(pl - 1));
                lo = (int)floorf(pos);
                hi = min(lo + 1, pl - 1);
                wg = pos - (float)lo;
            }
            int v0 = (int)(keys[b * pl + lo] & 0xFFFFFFFFull);
            int v1 = (int)(keys[b * pl + hi] & 0xFFFFFFFFull);
            const float4* e0 = (const float4*)(emb + (size_t)v0 * 32);
            const float4* e1 = (const float4*)(emb + (size_t)v1 * 32);
            float om = 1.0f - wg;
#pragma unroll
            for (int i4 = 0; i4 < 8; ++i4) {
                float4 a = e0[i4]; float4 c = e1[i4];
                hs[(i4*4+0) * 68 + t] = a.x * om + c.x * wg;
                hs[(i4*4+1) * 68 + t] = a.y * om + c.y * wg;
                hs[(i4*4+2) * 68 + t] = a.z * om + c.z * wg;
                hs[(i4*4+3) * 68 + t] = a.w * om + c.w * wg;
            }
        }
    }
    __syncthreads();

    const int o  = t >> 3;
    const int lg = t & 7;
    const float* wrow = &w_s[o * 96];
    float acc[8];
#pragma unroll
    for (int u = 0; u < 8; ++u) acc[u] = 0.f;
    const int hbase = lg * 8;

    for (int i = 0; i < 32; ++i) {
        float w0 = wrow[i * 3 + 0], w1 = wrow[i * 3 + 1], w2 = wrow[i * 3 + 2];
        const float* hrow = &hs[i * 68 + hbase];
        float hw[10];
#pragma unroll
        for (int x = 0; x < 10; ++x) hw[x] = hrow[x];
#pragma unroll
        for (int u = 0; u < 8; ++u) {
            acc[u] = fmaf(w0, hw[u], acc[u]);
            acc[u] = fmaf(w1, hw[u + 1], acc[u]);
            acc[u] = fmaf(w2, hw[u + 2], acc[u]);
        }
    }

    float lsum = 0.f;
    float frv[8];
    const int gbase = (b * 32 + o) * LDIM + l0 + lg * 8;
#pragma unroll
    for (int u = 0; u < 8; ++u) {
        float hval = hs[o * 68 + lg * 8 + 1 + u];
        float y = acc[u] + b_s[o];
        float ph = 0.5f * hval + 0.5f * y;
        int gi = gbase + u;
        float fh = f_hat[gi] + ph;
        f_hat[gi] = fh;
        float fr = f_rest[gi] - ph;
        f_rest[gi] = fr;
        frv[u] = fr;
        float df = fh - f[gi];
        lsum = fmaf(df, df, lsum);
    }

    if (zh_next) {
        __syncthreads();
#pragma unroll
        for (int u = 0; u < 8; ++u) hs[o * 68 + lg * 8 + u] = frv[u];
        __syncthreads();
        int npos = 64 / s_next;
        int qn_base = b * (LDIM / s_next) + l0 / s_next;
        for (int v = t; v < npos * 32; v += 256) {
            int jl = v >> 5, c = v & 31;
            float zv;
            if (s_next == 1) zv = hs[c * 68 + jl];
            else {
                int cl = jl * s_next + (s_next >> 1) - 1;
                zv = 0.5f * (hs[c * 68 + cl] + hs[c * 68 + cl + 1]);
            }
            _Float16 h = (_Float16)zv;
            float r = zv - (float)h;
            size_t zi = (size_t)(qn_base + jl) * 32 + c;
            zh_next[zi] = h;
            zl_next[zi] = (_Float16)r;
        }
    }

#pragma unroll
    for (int off = 32; off > 0; off >>= 1) lsum += __shfl_down(lsum, off, 64);
    if ((t & 63) == 0) red[t >> 6] = lsum;
    __syncthreads();
    if (t == 0) {
        atomicAdd(loss_acc, red[0] + red[1] + red[2] + red[3]);
        if (out_loss) {
            __threadfence();
            unsigned old = atomicAdd(done_ctr, 1u);
            if (old == (unsigned)(gridDim.x * gridDim.y - 1)) {
                float lv = atomicAdd(loss_acc, 0.0f);
                *out_loss = lv * (1.25f / (6.0f * (float)BCL));
            }
        }
    }
}

// ---------------------------------------------------------------- launch
extern "C" void kernel_launch(void* const* d_in, const int* in_sizes, int n_in,
                              void* d_out, int out_size, void* d_ws, size_t ws_size,
                              hipStream_t stream)
{
    const float* f    = (const float*)d_in[0];
    const float* emb  = (const float*)d_in[1];
    const float* phiw = (const float*)d_in[2];
    const float* phib = (const float*)d_in[3];

    float* f_hat    = (float*)d_out;
    float* out_loss = f_hat + BCL;

    const int pls[6]   = {1, 4, 16, 64, 256, 1024};
    const int lpls[6]  = {0, 2, 4, 6, 8, 10};
    const int vch[6]   = {64, 64, 64, 64, 32, 32};   // scan-path chunks (VC<=128)
    const int vchm[6]  = {0, 0, 64, 32, 16, 16};     // mfma-path chunks
    const int pidx[6]  = {0, 0, 1, 2, 3, 3};
    const int snx[6]   = {256, 64, 16, 4, 1, 0};

    char* ws = (char*)d_ws;
    float* f_rest = (float*)ws;

    // Layout (mf): f_rest | keysA+B 512K | z_hi 2M | z_lo 2M | e_hi 256K | e_lo 256K | e_sq | loss | ctr
    size_t base = (size_t)BCL * 4;
    size_t off = base;
    unsigned long long* keysA = (unsigned long long*)(ws + off);
    unsigned long long* keysB = keysA + 32768;
    off += (size_t)65536 * 8;
    _Float16* z_hi = (_Float16*)(ws + off); off += (size_t)32768 * 32 * 2;
    _Float16* z_lo = (_Float16*)(ws + off); off += (size_t)32768 * 32 * 2;
    _Float16* e_hi = (_Float16*)(ws + off); off += (size_t)VDIM * 32 * 2;
    _Float16* e_lo = (_Float16*)(ws + off); off += (size_t)VDIM * 32 * 2;
    size_t need_mf = off + (size_t)VDIM * 4 + 64;
    bool mf = ws_size >= need_mf;

    if (!mf) {  // fallback layout: f_rest | keysA(+B) | e_sq...
        off = base;
        size_t need_pp = base + (size_t)65536 * 8 + (size_t)VDIM * 4 + 64;
        bool pp = ws_size >= need_pp;
        keysB = pp ? keysA + 32768 : keysA;
        off += pp ? (size_t)65536 * 8 : (size_t)32768 * 8;
        float* e_sq        = (float*)(ws + off);
        float* loss_acc    = e_sq + VDIM;
        unsigned* done_ctr = (unsigned*)(loss_acc + 1);

        init_kernel<<<dim3((BCL + 255) / 256), 256, 0, stream>>>(
            f, emb, f_rest, f_hat, e_sq, nullptr, nullptr, loss_acc, done_ctr, keysA, 32768);

        for (int si = 0; si < 6; ++si) {
            int pl = pls[si], s = LDIM / pl, NQ = BDIM * pl;
            int qgroups = (NQ + 511) >> 9;
            int VC = VDIM / vch[si];
            unsigned long long* k  = (si & 1) ? keysB : keysA;
            unsigned long long* kn = (si < 5 && pp) ? ((si & 1) ? keysA : keysB) : nullptr;
            int nq_next = (si < 5) ? BDIM * pls[si + 1] : 0;
            if (!pp && si > 0) hipMemsetAsync(k, 0xFF, (size_t)NQ * 8, stream);
            vq_scan<<<dim3(qgroups * vch[si]), 256, 0, stream>>>(
                f_rest, nullptr, emb, e_sq, k, lpls[si], s, NQ, VC, vch[si]);
            fuse_kernel<<<dim3(16, 32), 256, 0, stream>>>(
                f, emb, k, kn, nq_next, nullptr, nullptr, snx[si],
                phiw + (size_t)pidx[si] * 3072, phib + (size_t)pidx[si] * 32,
                f_rest, f_hat, loss_acc, done_ctr,
                (si == 5) ? out_loss : nullptr, pl);
        }
        return;
    }

    float* e_sq        = (float*)(ws + off);
    float* loss_acc    = e_sq + VDIM;
    unsigned* done_ctr = (unsigned*)(loss_acc + 1);

    init_kernel<<<dim3((BCL + 255) / 256), 256, 0, stream>>>(
        f, emb, f_rest, f_hat, e_sq, e_hi, e_lo, loss_acc, done_ctr, keysA, 32768);

    for (int si = 0; si < 6; ++si) {
        int pl = pls[si], s = LDIM / pl, NQ = BDIM * pl;
        unsigned long long* k  = (si & 1) ? keysB : keysA;
        unsigned long long* kn = (si < 5) ? ((si & 1) ? keysA : keysB) : nullptr;
        int nq_next = (si < 5) ? BDIM * pls[si + 1] : 0;
        if (si >= 2) {
            int vcm = vchm[si];
            vq_mfma<<<dim3((NQ / 128) * vcm), 256, 0, stream>>>(
                z_hi, z_lo, e_hi, e_lo, e_sq, k, NQ, VDIM / vcm, vcm);
        } else {
            int qgroups = (NQ + 511) >> 9;
            vq_scan<<<dim3(qgroups * vch[si]), 256, 0, stream>>>(
                f_rest, nullptr, emb, e_sq, k, lpls[si], s, NQ, VDIM / vch[si], vch[si]);
        }
        bool zw = (si >= 1 && si <= 4);
        fuse_kernel<<<dim3(16, 32), 256, 0, stream>>>(
            f, emb, k, kn, nq_next,
            zw ? z_hi : nullptr, zw ? z_lo : nullptr, snx[si],
            phiw + (size_t)pidx[si] * 3072, phib + (size_t)pidx[si] * 32,
            f_rest, f_hat, loss_acc, done_ctr,
            (si == 5) ? out_loss : nullptr, pl);
    }
}

// Round 17
// 314.397 us; speedup vs baseline: 1.3595x; 1.0136x over previous
//
#include <hip/hip_runtime.h>
#include <stdint.h>

#define BDIM 32
#define CDIM 32
#define LDIM 1024
#define VDIM 4096
#define BCL (BDIM*CDIM*LDIM)

typedef _Float16 f16x8 __attribute__((ext_vector_type(8)));
typedef float f32x4 __attribute__((ext_vector_type(4)));

// zero-cost pin (scalar floats only; float4 "+v" doesn't compile - r13)
#define PIN_V(x) asm volatile("" : "+v"(x))

// ---------------------------------------------------------------- init
// eh/el hold the exact 2-way fp16 split of -2*emb (power-of-2 scale is exact):
// h = fp16(-2v), l = fp16(-2*(v - fp16(v))). Distance d = e_sq + z.(-2e).
__global__ void init_kernel(const float* __restrict__ f, const float* __restrict__ emb,
                            float* __restrict__ f_rest, float* __restrict__ f_hat,
                            float* __restrict__ e_sq,
                            _Float16* __restrict__ eh, _Float16* __restrict__ el,
                            float* __restrict__ loss_acc, unsigned* __restrict__ done_ctr,
                            unsigned long long* __restrict__ keys, int nkeys) {
    int i = blockIdx.x * blockDim.x + threadIdx.x;
    if (i < BCL) { f_rest[i] = f[i]; f_hat[i] = 0.0f; }
    if (i < VDIM) {
        const float* e = emb + (size_t)i * CDIM;
        float s = 0.f;
#pragma unroll
        for (int k = 0; k < 32; ++k) {
            float v = e[k];
            s = fmaf(v, v, s);
            if (eh) {
                _Float16 h = (_Float16)v;
                float r = v - (float)h;
                eh[(size_t)i*32 + k] = (_Float16)(-2.0f) * h;
                el[(size_t)i*32 + k] = (_Float16)(-2.0f) * (_Float16)r;
            }
        }
        e_sq[i] = s;
    }
    if (i < nkeys) keys[i] = ~0ull;
    if (i == 0) { *loss_acc = 0.f; *done_ctr = 0u; }
}

// ---------------------------------------------------------------- VQ argmin via MFMA (si>=2)
// r16 counters: MfmaUtil 29%, BANK_CONFLICT 2.1M -- B-frag reads at 64B row stride put
// lanes 0-15 in 2 bank groups = 8-way conflict; LDS pipe (~720 cy/CU/iter) > MFMA
// (~400 cy/SIMD/iter) was the binding resource.
// ROUND-17 fixes (isolated to this kernel + init):
//  (a) XOR swizzle: float4 col c -> c ^ ((row>>1)&3) on store AND read. Bank groups for
//      rows 0..15 become {0,4,1,5,2,6,3,7}x2 = 2-way (free).
//  (b) -2 folded into the e split (exact), e_sq pre-loaded into the MFMA accumulator
//      (C/D col = code; all 4 lane elements share one code) -> epilogue = compare only.
// Layouts (m89-verified): A row=l&15,k=(l>>4)*8+j; B col=l&15 same k; C/D col=l&15,
// row=(l>>4)*4+i. Block: 4 waves x 2 q-tiles = 128 q. Argmin: per-lane, shfl_xor min,
// 1 atomicMin/q/chunk. Strict <, ascending v => first-index tie-break preserved.
__global__ __launch_bounds__(256) void vq_mfma(
    const _Float16* __restrict__ z_hi, const _Float16* __restrict__ z_lo,
    const _Float16* __restrict__ e_hi, const _Float16* __restrict__ e_lo,
    const float* __restrict__ e_sq, unsigned long long* __restrict__ keys,
    int NQ, int VC, int vchunks)
{
    const int t = threadIdx.x;
    const int lane = t & 63;
    const int w = t >> 6;
    const int qg = blockIdx.x / vchunks;
    const int vc = blockIdx.x % vchunks;
    const int vb = vc * VC;

    __shared__ __align__(16) _Float16 eh_ls[256*32];   // 16 KB
    __shared__ __align__(16) _Float16 el_ls[256*32];   // 16 KB
    __shared__ float esq_ls[256];

    {
        const float4* sH = (const float4*)(e_hi + (size_t)vb*32);
        const float4* sL = (const float4*)(e_lo + (size_t)vb*32);
        float4* dH = (float4*)eh_ls; float4* dL = (float4*)el_ls;
        int n4 = VC * 4;                 // 4 float4 per 32-half row
        for (int x = t; x < n4; x += 256) {
            int row = x >> 2, c = x & 3;
            int ds = row*4 + (c ^ ((row >> 1) & 3));   // swizzled float4 slot
            dH[ds] = sH[x]; dL[ds] = sL[x];
        }
        for (int v = t; v < VC; v += 256) esq_ls[v] = e_sq[vb + v];
    }

    const int fr = lane & 15;            // fragment row/col
    const int kq = lane >> 4;            // k-block (8 channels)
    const int qbase = qg*128 + w*32;     // NQ multiple of 128 for si>=2: no tail
    const int q0 = qbase + fr;
    f16x8 a0h = *(const f16x8*)(z_hi + (size_t)q0*32 + kq*8);
    f16x8 a0l = *(const f16x8*)(z_lo + (size_t)q0*32 + kq*8);
    f16x8 a1h = *(const f16x8*)(z_hi + (size_t)(q0+16)*32 + kq*8);
    f16x8 a1l = *(const f16x8*)(z_lo + (size_t)(q0+16)*32 + kq*8);

    __syncthreads();

    float bd0[4], bd1[4]; int bv0[4], bv1[4];
#pragma unroll
    for (int i = 0; i < 4; ++i) { bd0[i]=3.4e38f; bd1[i]=3.4e38f; bv0[i]=0; bv1[i]=0; }

    for (int vt = 0; vt < VC; vt += 16) {
        const int row = vt + fr;
        const int koff = (kq ^ ((row >> 1) & 3)) * 8;      // swizzled half offset
        const f16x8 bh = *(const f16x8*)(eh_ls + (size_t)row*32 + koff);
        const f16x8 bl = *(const f16x8*)(el_ls + (size_t)row*32 + koff);
        float es = esq_ls[row];
        f32x4 acc0 = {es, es, es, es};     // d starts at e_sq (C col = code)
        f32x4 acc1 = {es, es, es, es};
        acc0 = __builtin_amdgcn_mfma_f32_16x16x32_f16(a0h, bh, acc0, 0,0,0);
        acc0 = __builtin_amdgcn_mfma_f32_16x16x32_f16(a0h, bl, acc0, 0,0,0);
        acc0 = __builtin_amdgcn_mfma_f32_16x16x32_f16(a0l, bh, acc0, 0,0,0);
        acc0 = __builtin_amdgcn_mfma_f32_16x16x32_f16(a0l, bl, acc0, 0,0,0);
        acc1 = __builtin_amdgcn_mfma_f32_16x16x32_f16(a1h, bh, acc1, 0,0,0);
        acc1 = __builtin_amdgcn_mfma_f32_16x16x32_f16(a1h, bl, acc1, 0,0,0);
        acc1 = __builtin_amdgcn_mfma_f32_16x16x32_f16(a1l, bh, acc1, 0,0,0);
        acc1 = __builtin_amdgcn_mfma_f32_16x16x32_f16(a1l, bl, acc1, 0,0,0);

        int vg = vb + row;
#pragma unroll
        for (int i = 0; i < 4; ++i) {
            if (acc0[i] < bd0[i]) { bd0[i] = acc0[i]; bv0[i] = vg; }
            if (acc1[i] < bd1[i]) { bd1[i] = acc1[i]; bv1[i] = vg; }
        }
    }

    // cross-lane argmin: group g=lanes 16g..16g+15 holds rows 4g..4g+3, cols 0..15
#pragma unroll
    for (int i = 0; i < 4; ++i) {
        unsigned u0 = __float_as_uint(bd0[i]);
        u0 = (u0 & 0x80000000u) ? ~u0 : (u0 | 0x80000000u);
        unsigned long long k0 = ((unsigned long long)u0 << 32) | (unsigned)bv0[i];
        unsigned u1 = __float_as_uint(bd1[i]);
        u1 = (u1 & 0x80000000u) ? ~u1 : (u1 | 0x80000000u);
        unsigned long long k1 = ((unsigned long long)u1 << 32) | (unsigned)bv1[i];
#pragma unroll
        for (int m = 1; m < 16; m <<= 1) {
            unsigned long long o0 = __shfl_xor(k0, m, 64); if (o0 < k0) k0 = o0;
            unsigned long long o1 = __shfl_xor(k1, m, 64); if (o1 < k1) k1 = o1;
        }
        if (fr == 0) {
            int q = qbase + kq*4 + i;
            atomicMin(&keys[q], k0);
            atomicMin(&keys[q + 16], k1);
        }
    }
}

// ---------------------------------------------------------------- VQ argmin: lane-per-query scan
// (kept for si 0,1 -- NQ=32/128, reads f_rest directly -- and as fallback.)
__global__ __launch_bounds__(256) void vq_scan(
    const float* __restrict__ f_rest, const float* __restrict__ z_buf,
    const float* __restrict__ emb, const float* __restrict__ e_sq,
    unsigned long long* __restrict__ keys,
    int lpl, int s, int NQ, int VC, int vchunks)
{
    const int pl = 1 << lpl;
    const int t  = threadIdx.x;
    const int qg = blockIdx.x / vchunks;
    const int vc = blockIdx.x % vchunks;
    const int vb = vc * VC;

    __shared__ __align__(16) float e_ls[128 * 32];
    __shared__ float esq_ls[128];

    {
        const float4* src = (const float4*)emb + (size_t)vb * 8;
        float4* dst = (float4*)e_ls;
        for (int x = t; x < VC * 8; x += 256) dst[x] = src[x];
        if (t < VC) esq_ls[t] = e_sq[vb + t];
    }

    const int q0 = qg * 512 + t;
    const int q1 = q0 + 256;
    const int qc0 = (q0 < NQ) ? q0 : NQ - 1;
    const int qc1 = (q1 < NQ) ? q1 : NQ - 1;

    float z0[32], z1[32];
    if (z_buf) {
        const float4* p0 = (const float4*)(z_buf + (size_t)qc0 * 32);
        const float4* p1 = (const float4*)(z_buf + (size_t)qc1 * 32);
#pragma unroll
        for (int c4 = 0; c4 < 8; ++c4) {
            float4 a = p0[c4], b = p1[c4];
            z0[c4*4+0] = a.x; z0[c4*4+1] = a.y; z0[c4*4+2] = a.z; z0[c4*4+3] = a.w;
            z1[c4*4+0] = b.x; z1[c4*4+1] = b.y; z1[c4*4+2] = b.z; z1[c4*4+3] = b.w;
        }
    } else {
        int b0 = qc0 >> lpl, j0 = qc0 & (pl - 1);
        int b1 = qc1 >> lpl, j1 = qc1 & (pl - 1);
        if (pl == LDIM) {
            const float* p0 = f_rest + b0 * (CDIM * LDIM) + j0;
            const float* p1 = f_rest + b1 * (CDIM * LDIM) + j1;
#pragma unroll
            for (int c = 0; c < 32; ++c) { z0[c] = p0[c * LDIM]; z1[c] = p1[c * LDIM]; }
        } else {
            int col0 = j0 * s + (s >> 1) - 1;
            int col1 = j1 * s + (s >> 1) - 1;
            const float* p0 = f_rest + b0 * (CDIM * LDIM) + col0;
            const float* p1 = f_rest + b1 * (CDIM * LDIM) + col1;
#pragma unroll
            for (int c = 0; c < 32; ++c) {
                z0[c] = 0.5f * (p0[c * LDIM] + p0[c * LDIM + 1]);
                z1[c] = 0.5f * (p1[c * LDIM] + p1[c * LDIM + 1]);
            }
        }
    }

    __syncthreads();

    float bd0 = 3.4e38f, bd1 = 3.4e38f;
    int bv0 = 0, bv1 = 0;

#pragma unroll 1
    for (int v = 0; v < VC; v += 2) {
#pragma unroll
        for (int c = 0; c < 32; ++c) { PIN_V(z0[c]); PIN_V(z1[c]); }

        const float4* er0 = (const float4*)&e_ls[(size_t)v * 32];
        const float4* er1 = er0 + 8;
        float es0 = esq_ls[v];
        float es1 = esq_ls[v + 1];

        float4 e0 = er0[0], e1 = er1[0];
        float a00 = z0[0] * e0.x,        a01 = z0[0] * e1.x;
        float a10 = z1[0] * e0.x,        a11 = z1[0] * e1.x;
        a00 = fmaf(z0[1], e0.y, a00);    a01 = fmaf(z0[1], e1.y, a01);
        a10 = fmaf(z1[1], e0.y, a10);    a11 = fmaf(z1[1], e1.y, a11);
        a00 = fmaf(z0[2], e0.z, a00);    a01 = fmaf(z0[2], e1.z, a01);
        a10 = fmaf(z1[2], e0.z, a10);    a11 = fmaf(z1[2], e1.z, a11);
        a00 = fmaf(z0[3], e0.w, a00);    a01 = fmaf(z0[3], e1.w, a01);
        a10 = fmaf(z1[3], e0.w, a10);    a11 = fmaf(z1[3], e1.w, a11);
#pragma unroll
        for (int c4 = 1; c4 < 8; ++c4) {
            e0 = er0[c4]; e1 = er1[c4];
            a00 = fmaf(z0[c4*4+0], e0.x, a00);  a01 = fmaf(z0[c4*4+0], e1.x, a01);
            a10 = fmaf(z1[c4*4+0], e0.x, a10);  a11 = fmaf(z1[c4*4+0], e1.x, a11);
            a00 = fmaf(z0[c4*4+1], e0.y, a00);  a01 = fmaf(z0[c4*4+1], e1.y, a01);
            a10 = fmaf(z1[c4*4+1], e0.y, a10);  a11 = fmaf(z1[c4*4+1], e1.y, a11);
            a00 = fmaf(z0[c4*4+2], e0.z, a00);  a01 = fmaf(z0[c4*4+2], e1.z, a01);
            a10 = fmaf(z1[c4*4+2], e0.z, a10);  a11 = fmaf(z1[c4*4+2], e1.z, a11);
            a00 = fmaf(z0[c4*4+3], e0.w, a00);  a01 = fmaf(z0[c4*4+3], e1.w, a01);
            a10 = fmaf(z1[c4*4+3], e0.w, a10);  a11 = fmaf(z1[c4*4+3], e1.w, a11);
        }
        float d00 = fmaf(a00, -2.0f, es0);
        float d01 = fmaf(a01, -2.0f, es1);
        float d10 = fmaf(a10, -2.0f, es0);
        float d11 = fmaf(a11, -2.0f, es1);
        if (d00 < bd0) { bd0 = d00; bv0 = vb + v; }
        if (d01 < bd0) { bd0 = d01; bv0 = vb + v + 1; }
        if (d10 < bd1) { bd1 = d10; bv1 = vb + v; }
        if (d11 < bd1) { bd1 = d11; bv1 = vb + v + 1; }
    }

    if (q0 < NQ) {
        unsigned ud = __float_as_uint(bd0);
        ud = (ud & 0x80000000u) ? ~ud : (ud | 0x80000000u);
        atomicMin(&keys[q0], ((unsigned long long)ud << 32) | (unsigned)bv0);
    }
    if (q1 < NQ) {
        unsigned ud = __float_as_uint(bd1);
        ud = (ud & 0x80000000u) ? ~ud : (ud | 0x80000000u);
        atomicMin(&keys[q1], ((unsigned long long)ud << 32) | (unsigned)bv1);
    }
}

// ---------------------------------------------------------------- fused gather+upsample+phi+update+loss
// 64-element L-chunks (grid 16 x 32). Resets next scale's key buffer (ping-pong);
// writes next scale's downsampled queries as fp16 hi/lo split (exact 2-way split:
// h=fp16(zv), l=fp16(zv-(float)h)); last scale finalizes the loss via done-counter.
__global__ __launch_bounds__(256) void fuse_kernel(
    const float* __restrict__ f, const float* __restrict__ emb,
    const unsigned long long* __restrict__ keys,
    unsigned long long* __restrict__ keys_next, int nq_next,
    _Float16* __restrict__ zh_next, _Float16* __restrict__ zl_next, int s_next,
    const float* __restrict__ w, const float* __restrict__ bias,
    float* __restrict__ f_rest, float* __restrict__ f_hat,
    float* __restrict__ loss_acc, unsigned* __restrict__ done_ctr,
    float* __restrict__ out_loss, int pl)
{
    const int t  = threadIdx.x;
    const int b  = blockIdx.y;
    const int l0 = blockIdx.x * 64;

    if (keys_next) {
        int x = (b * gridDim.x + blockIdx.x) * 256 + t;
        if (x < nq_next) keys_next[x] = ~0ull;
    }

    __shared__ float w_s[3072];
    __shared__ float b_s[32];
    __shared__ float hs[32 * 68];
    __shared__ float red[4];

    for (int x = t; x < 3072; x += 256) w_s[x] = w[x];
    if (t < 32) b_s[t] = bias[t];

    if (t < 66) {
        int l = l0 - 1 + t;
        if (l < 0 || l >= LDIM) {
#pragma unroll
            for (int i = 0; i < 32; ++i) hs[i * 68 + t] = 0.f;
        } else {
            int lo, hi; float wg;
            if (pl == LDIM) { lo = l; hi = l; wg = 0.f; }
            else {
                float pos = (l + 0.5f) * ((float)pl / 1024.0f) - 0.5f;
                pos = fminf(fmaxf(pos, 0.f), (float)(pl - 1));
                lo = (int)floorf(pos);
                hi = min(lo + 1, pl - 1);
                wg = pos - (float)lo;
            }
            int v0 = (int)(keys[b * pl + lo] & 0xFFFFFFFFull);
            int v1 = (int)(keys[b * pl + hi] & 0xFFFFFFFFull);
            const float4* e0 = (const float4*)(emb + (size_t)v0 * 32);
            const float4* e1 = (const float4*)(emb + (size_t)v1 * 32);
            float om = 1.0f - wg;
#pragma unroll
            for (int i4 = 0; i4 < 8; ++i4) {
                float4 a = e0[i4]; float4 c = e1[i4];
                hs[(i4*4+0) * 68 + t] = a.x * om + c.x * wg;
                hs[(i4*4+1) * 68 + t] = a.y * om + c.y * wg;
                hs[(i4*4+2) * 68 + t] = a.z * om + c.z * wg;
                hs[(i4*4+3) * 68 + t] = a.w * om + c.w * wg;
            }
        }
    }
    __syncthreads();

    const int o  = t >> 3;
    const int lg = t & 7;
    const float* wrow = &w_s[o * 96];
    float acc[8];
#pragma unroll
    for (int u = 0; u < 8; ++u) acc[u] = 0.f;
    const int hbase = lg * 8;

    for (int i = 0; i < 32; ++i) {
        float w0 = wrow[i * 3 + 0], w1 = wrow[i * 3 + 1], w2 = wrow[i * 3 + 2];
        const float* hrow = &hs[i * 68 + hbase];
        float hw[10];
#pragma unroll
        for (int x = 0; x < 10; ++x) hw[x] = hrow[x];
#pragma unroll
        for (int u = 0; u < 8; ++u) {
            acc[u] = fmaf(w0, hw[u], acc[u]);
            acc[u] = fmaf(w1, hw[u + 1], acc[u]);
            acc[u] = fmaf(w2, hw[u + 2], acc[u]);
        }
    }

    float lsum = 0.f;
    float frv[8];
    const int gbase = (b * 32 + o) * LDIM + l0 + lg * 8;
#pragma unroll
    for (int u = 0; u < 8; ++u) {
        float hval = hs[o * 68 + lg * 8 + 1 + u];
        float y = acc[u] + b_s[o];
        float ph = 0.5f * hval + 0.5f * y;
        int gi = gbase + u;
        float fh = f_hat[gi] + ph;
        f_hat[gi] = fh;
        float fr = f_rest[gi] - ph;
        f_rest[gi] = fr;
        frv[u] = fr;
        float df = fh - f[gi];
        lsum = fmaf(df, df, lsum);
    }

    if (zh_next) {
        __syncthreads();
#pragma unroll
        for (int u = 0; u < 8; ++u) hs[o * 68 + lg * 8 + u] = frv[u];
        __syncthreads();
        int npos = 64 / s_next;
        int qn_base = b * (LDIM / s_next) + l0 / s_next;
        for (int v = t; v < npos * 32; v += 256) {
            int jl = v >> 5, c = v & 31;
            float zv;
            if (s_next == 1) zv = hs[c * 68 + jl];
            else {
                int cl = jl * s_next + (s_next >> 1) - 1;
                zv = 0.5f * (hs[c * 68 + cl] + hs[c * 68 + cl + 1]);
            }
            _Float16 h = (_Float16)zv;
            float r = zv - (float)h;
            size_t zi = (size_t)(qn_base + jl) * 32 + c;
            zh_next[zi] = h;
            zl_next[zi] = (_Float16)r;
        }
    }

#pragma unroll
    for (int off = 32; off > 0; off >>= 1) lsum += __shfl_down(lsum, off, 64);
    if ((t & 63) == 0) red[t >> 6] = lsum;
    __syncthreads();
    if (t == 0) {
        atomicAdd(loss_acc, red[0] + red[1] + red[2] + red[3]);
        if (out_loss) {
            __threadfence();
            unsigned old = atomicAdd(done_ctr, 1u);
            if (old == (unsigned)(gridDim.x * gridDim.y - 1)) {
                float lv = atomicAdd(loss_acc, 0.0f);
                *out_loss = lv * (1.25f / (6.0f * (float)BCL));
            }
        }
    }
}

// ---------------------------------------------------------------- launch
extern "C" void kernel_launch(void* const* d_in, const int* in_sizes, int n_in,
                              void* d_out, int out_size, void* d_ws, size_t ws_size,
                              hipStream_t stream)
{
    const float* f    = (const float*)d_in[0];
    const float* emb  = (const float*)d_in[1];
    const float* phiw = (const float*)d_in[2];
    const float* phib = (const float*)d_in[3];

    float* f_hat    = (float*)d_out;
    float* out_loss = f_hat + BCL;

    const int pls[6]   = {1, 4, 16, 64, 256, 1024};
    const int lpls[6]  = {0, 2, 4, 6, 8, 10};
    const int vch[6]   = {64, 64, 64, 64, 32, 32};   // scan-path chunks (VC<=128)
    const int vchm[6]  = {0, 0, 64, 32, 16, 16};     // mfma-path chunks
    const int pidx[6]  = {0, 0, 1, 2, 3, 3};
    const int snx[6]   = {256, 64, 16, 4, 1, 0};

    char* ws = (char*)d_ws;
    float* f_rest = (float*)ws;

    // Layout (mf): f_rest | keysA+B 512K | z_hi 2M | z_lo 2M | e_hi 256K | e_lo 256K | e_sq | loss | ctr
    size_t base = (size_t)BCL * 4;
    size_t off = base;
    unsigned long long* keysA = (unsigned long long*)(ws + off);
    unsigned long long* keysB = keysA + 32768;
    off += (size_t)65536 * 8;
    _Float16* z_hi = (_Float16*)(ws + off); off += (size_t)32768 * 32 * 2;
    _Float16* z_lo = (_Float16*)(ws + off); off += (size_t)32768 * 32 * 2;
    _Float16* e_hi = (_Float16*)(ws + off); off += (size_t)VDIM * 32 * 2;
    _Float16* e_lo = (_Float16*)(ws + off); off += (size_t)VDIM * 32 * 2;
    size_t need_mf = off + (size_t)VDIM * 4 + 64;
    bool mf = ws_size >= need_mf;

    if (!mf) {  // fallback layout: f_rest | keysA(+B) | e_sq...
        off = base;
        size_t need_pp = base + (size_t)65536 * 8 + (size_t)VDIM * 4 + 64;
        bool pp = ws_size >= need_pp;
        keysB = pp ? keysA + 32768 : keysA;
        off += pp ? (size_t)65536 * 8 : (size_t)32768 * 8;
        float* e_sq        = (float*)(ws + off);
        float* loss_acc    = e_sq + VDIM;
        unsigned* done_ctr = (unsigned*)(loss_acc + 1);

        init_kernel<<<dim3((BCL + 255) / 256), 256, 0, stream>>>(
            f, emb, f_rest, f_hat, e_sq, nullptr, nullptr, loss_acc, done_ctr, keysA, 32768);

        for (int si = 0; si < 6; ++si) {
            int pl = pls[si], s = LDIM / pl, NQ = BDIM * pl;
            int qgroups = (NQ + 511) >> 9;
            int VC = VDIM / vch[si];
            unsigned long long* k  = (si & 1) ? keysB : keysA;
            unsigned long long* kn = (si < 5 && pp) ? ((si & 1) ? keysA : keysB) : nullptr;
            int nq_next = (si < 5) ? BDIM * pls[si + 1] : 0;
            if (!pp && si > 0) hipMemsetAsync(k, 0xFF, (size_t)NQ * 8, stream);
            vq_scan<<<dim3(qgroups * vch[si]), 256, 0, stream>>>(
                f_rest, nullptr, emb, e_sq, k, lpls[si], s, NQ, VC, vch[si]);
            fuse_kernel<<<dim3(16, 32), 256, 0, stream>>>(
                f, emb, k, kn, nq_next, nullptr, nullptr, snx[si],
                phiw + (size_t)pidx[si] * 3072, phib + (size_t)pidx[si] * 32,
                f_rest, f_hat, loss_acc, done_ctr,
                (si == 5) ? out_loss : nullptr, pl);
        }
        return;
    }

    float* e_sq        = (float*)(ws + off);
    float* loss_acc    = e_sq + VDIM;
    unsigned* done_ctr = (unsigned*)(loss_acc + 1);

    init_kernel<<<dim3((BCL + 255) / 256), 256, 0, stream>>>(
        f, emb, f_rest, f_hat, e_sq, e_hi, e_lo, loss_acc, done_ctr, keysA, 32768);

    for (int si = 0; si < 6; ++si) {
        int pl = pls[si], s = LDIM / pl, NQ = BDIM * pl;
        unsigned long long* k  = (si & 1) ? keysB : keysA;
        unsigned long long* kn = (si < 5) ? ((si & 1) ? keysA : keysB) : nullptr;
        int nq_next = (si < 5) ? BDIM * pls[si + 1] : 0;
        if (si >= 2) {
            int vcm = vchm[si];
            vq_mfma<<<dim3((NQ / 128) * vcm), 256, 0, stream>>>(
                z_hi, z_lo, e_hi, e_lo, e_sq, k, NQ, VDIM / vcm, vcm);
        } else {
            int qgroups = (NQ + 511) >> 9;
            vq_scan<<<dim3(qgroups * vch[si]), 256, 0, stream>>>(
                f_rest, nullptr, emb, e_sq, k, lpls[si], s, NQ, VDIM / vch[si], vch[si]);
        }
        bool zw = (si >= 1 && si <= 4);
        fuse_kernel<<<dim3(16, 32), 256, 0, stream>>>(
            f, emb, k, kn, nq_next,
            zw ? z_hi : nullptr, zw ? z_lo : nullptr, snx[si],
            phiw + (size_t)pidx[si] * 3072, phib + (size_t)pidx[si] * 32,
            f_rest, f_hat, loss_acc, done_ctr,
            (si == 5) ? out_loss : nullptr, pl);
    }
}